// Round 1
// baseline (328.256 us; speedup 1.0000x reference)
//
#include <hip/hip_runtime.h>

#define K 64
#define S_CHUNK 256
#define W_BURN 128

// ws layout (float offsets)
#define WS_P      0       // P row-major [64][64]
#define WS_PI     4096    // stationary distribution
#define WS_UTT0   4160    // filtered dist at t=0
#define WS_MU     4224
#define WS_ISIG   4288    // 1/sigma
#define WS_GS16   4352    // 16 * inv_norm  (16 = constant growth factor folded into g)
#define WS_FT0    4416

__device__ __forceinline__ float waveReduceSum(float v) {
#pragma unroll
    for (int off = 32; off > 0; off >>= 1)
        v += __shfl_xor(v, off, 64);
    return v;
}

// One wave: softmax(P), stationary pi via power iteration, emission params, row-0 outputs.
__global__ __launch_bounds__(64) void hmm_setup(
    const float* __restrict__ y,
    const float* __restrict__ logits,
    const float* __restrict__ mu,
    const float* __restrict__ log_sigma,
    float* __restrict__ out, float* __restrict__ ws, int T)
{
    __shared__ float P[K][K];
    __shared__ float pib[K];
    const int k = threadIdx.x;  // 0..63, lane == row

    float row[K];
    float m = -3.4e38f;
#pragma unroll
    for (int i = 0; i < K; ++i) { row[i] = logits[k * K + i]; m = fmaxf(m, row[i]); }
    float s = 0.f;
#pragma unroll
    for (int i = 0; i < K; ++i) { row[i] = __expf(row[i] - m); s += row[i]; }
    float inv = 1.0f / s;
#pragma unroll
    for (int i = 0; i < K; ++i) { float p = row[i] * inv; P[k][i] = p; ws[WS_P + k * K + i] = p; }
    __syncthreads();

    pib[k] = 1.0f / (float)K;
    __syncthreads();
    for (int it = 0; it < 48; ++it) {
        float acc = 0.f;
#pragma unroll
        for (int j = 0; j < K; ++j) acc += pib[j] * P[j][k];  // (pi^T P)_k
        float tot = waveReduceSum(acc);
        acc = acc / tot;
        __syncthreads();
        pib[k] = acc;
        __syncthreads();
    }
    float pi_k = pib[k];

    float mu_k = mu[k];
    float sig = __expf(log_sigma[k]);
    float isg = 1.0f / sig;
    float inorm = isg * 0.39894228040143267f;  // 1/sqrt(2*pi) / sigma

    ws[WS_PI + k]   = pi_k;
    ws[WS_MU + k]   = mu_k;
    ws[WS_ISIG + k] = isg;
    ws[WS_GS16 + k] = inorm * 16.0f;

    float y0 = y[0];
    float z = (y0 - mu_k) * isg;
    float g0 = __expf(-0.5f * z * z) * inorm;
    float num = pi_k * g0;
    float ft0 = waveReduceSum(num);
    float utt0 = num / ft0;
    ws[WS_UTT0 + k] = utt0;
    if (k == 0) ws[WS_FT0] = ft0;

    float* out_un = out + (size_t)T * K;
    float* out_ft = out + (size_t)2 * T * K;
    out[k] = pi_k;          // ut[0]   = stationary (predicted)
    out_un[k] = utt0;       // unorm[0]
    if (k == 0) out_ft[0] = ft0;
}

// One wave per chunk of S_CHUNK output steps, W_BURN burn-in steps starting from pi.
// Unnormalized recursion beta_t = (beta_{t-1} @ P) * g_t * 16, exact pow2 rescale
// every 32 steps. Outputs are scale-invariant ratios.
__global__ __launch_bounds__(256, 4) void hmm_scan(
    const float* __restrict__ y,
    const float* __restrict__ ws,
    float* __restrict__ out, int T)
{
    __shared__ __align__(16) float beta_s[4][K];
    const int lane = threadIdx.x & 63;
    const int wid  = threadIdx.x >> 6;
    const int NCH  = (T + S_CHUNK - 1) / S_CHUNK;
    const int chunk = blockIdx.x * 4 + wid;
    if (chunk >= NCH) return;

    const int t0      = chunk * S_CHUNK;
    const int t_end   = min(t0 + S_CHUNK, T);
    const int t_begin = (chunk == 0) ? 0 : t0 - W_BURN;

    // P column `lane` into registers (coalesced across lanes, L2-cached)
    float Pc[K];
#pragma unroll
    for (int j = 0; j < K; ++j) Pc[j] = ws[WS_P + j * K + lane];

    const float mu_k = ws[WS_MU + lane];
    const float isg  = ws[WS_ISIG + lane];
    const float gs16 = ws[WS_GS16 + lane];

    float* bl = beta_s[wid];
    float beta0 = (chunk == 0) ? ws[WS_UTT0 + lane] : ws[WS_PI + lane];
    bl[lane] = beta0;
    float sp = waveReduceSum(beta0);  // sum of stored beta_{t-1}

    float ftk = 0.0f;                 // per-lane ft batch slot
    if (chunk == 0 && lane == 0) ftk = ws[WS_FT0];

    float* out_un = out + (size_t)T * K;
    float* out_ft = out + (size_t)2 * T * K;

    float ycur = y[t_begin + 1];
    for (int t = t_begin + 1; t < t_end; ++t) {
        float ynx = (t + 1 < t_end) ? y[t + 1] : 0.0f;  // prefetch (guarded, uniform)

        // v_k = sum_j beta[j] * P[j][lane]   (broadcast LDS reads)
        float a0 = 0.f, a1 = 0.f, a2 = 0.f, a3 = 0.f;
#pragma unroll
        for (int q = 0; q < 16; ++q) {
            float4 b = *reinterpret_cast<const float4*>(&bl[4 * q]);
            a0 = fmaf(b.x, Pc[4 * q + 0], a0);
            a1 = fmaf(b.y, Pc[4 * q + 1], a1);
            a2 = fmaf(b.z, Pc[4 * q + 2], a2);
            a3 = fmaf(b.w, Pc[4 * q + 3], a3);
        }
        float v = (a0 + a1) + (a2 + a3);

        float z  = (ycur - mu_k) * isg;
        float g  = __expf(-0.5f * z * z) * gs16;  // includes x16 growth factor
        float nb = v * g;
        bl[lane] = nb;  // store new beta ASAP (in-order DS: next iter reads after)

        const bool outp = (t >= t0);
        if (outp | ((t & 31) == 31)) {
            float st = waveReduceSum(nb);
            if (outp) {
                float rp = __builtin_amdgcn_rcpf(sp);
                float rs = __builtin_amdgcn_rcpf(st);
                size_t ob = (size_t)t * K + lane;
                __builtin_nontemporal_store(v * rp, &out[ob]);     // ut[t]
                __builtin_nontemporal_store(nb * rs, &out_un[ob]); // unorm[t]
                float ftv = st * rp * 0.0625f;                     // ft = s_t/(16*s_{t-1})
                int sl = (t - t0) & 63;
                if (sl == lane) ftk = ftv;
                if (sl == 63) __builtin_nontemporal_store(ftk, &out_ft[(t - 63) + lane]);
            }
            sp = st;
            if ((t & 31) == 31) {
                // exact power-of-2 rescale to keep beta in fp32 range
                unsigned eb = (__float_as_uint(st) >> 23) & 255u;
                float r2 = __uint_as_float((254u - eb) << 23);  // 2^(-exponent(st))
                float nb2 = nb * r2;
                bl[lane] = nb2;
                sp = st * r2;
            }
        }
        ycur = ynx;
    }
}

extern "C" void kernel_launch(void* const* d_in, const int* in_sizes, int n_in,
                              void* d_out, int out_size, void* d_ws, size_t ws_size,
                              hipStream_t stream) {
    const float* y      = (const float*)d_in[0];
    const float* logits = (const float*)d_in[1];
    const float* mu     = (const float*)d_in[2];
    const float* lsig   = (const float*)d_in[3];
    float* out = (float*)d_out;
    float* ws  = (float*)d_ws;
    const int T = in_sizes[0];

    hmm_setup<<<1, 64, 0, stream>>>(y, logits, mu, lsig, out, ws, T);

    const int nch = (T + S_CHUNK - 1) / S_CHUNK;
    const int nblocks = (nch + 3) / 4;  // 4 waves (chunks) per block
    hmm_scan<<<nblocks, 256, 0, stream>>>(y, ws, out, T);
}